// Round 9
// baseline (247.744 us; speedup 1.0000x reference)
//
#include <hip/hip_runtime.h>
#include <math.h>

// MoE Router V10: x(16384,2048) fp32, W(128,2048) fp32, bias(128) fp32
// out = [weights(16384,8) fp32 | indices(16384,8) as fp32]
//
// R12: split-K structure, occupancy fix + register A-fragments.
//  R11 post-mortem: counted vmcnt was neutralized (compiler drains vmcnt
//  before ds_read of gll-written LDS); logits stuck ~75us at 2 blocks/CU.
//  Floors: LDS ~23us, HBM ~20us, MFMA ~6us -> latency-bound, needs TLP.
//  Changes (arithmetic untouched -> bit-identical to R3/R10/R11):
//   - TOKT 128->64, 4 waves: grid 1024 = 4 blocks/CU = 16 waves/CU.
//   - A-fragments built in registers from coalesced global x (same split3
//     values/slots as the staged path); x never enters LDS -> no x barrier.
//   - W single-buffered 24 KB via 6x global_load_lds; 2 raw barriers/chunk
//     guard only the W image; counted vmcnt(4) keeps x prefetch in flight.
//   - __launch_bounds__(256,4) caps VGPR at 128 (est ~115).

#define NE     128
#define TOKT   64    // tokens per tile (kernel A)
#define KC     32    // k per chunk (one 16x16x32 MFMA step)
#define KS     4     // split-K
#define DMODEL 2048
#define DSLICE (DMODEL / KS)          // 512
#define NCH    (DSLICE / KC)          // 16 chunks per block
#define CHUNK_SH (3 * NE * KC)        // 12288 shorts per chunk image

typedef __attribute__((ext_vector_type(8))) short short8;
typedef __attribute__((ext_vector_type(4))) short s16x4;
typedef __attribute__((ext_vector_type(4))) float f32x4;

union S8  { short s[8]; short8 v; };
union S4u { short s[4]; s16x4 v; };

// split one fp32 into 3 truncated bf16 planes (exact residuals), slot j of 8
__device__ __forceinline__ void split3(float f, S8& hi, S8& mi, S8& lo, int j) {
  const unsigned u0 = __float_as_uint(f);
  const float hif = __uint_as_float(u0 & 0xFFFF0000u);
  const float r1 = f - hif;                      // exact
  const unsigned u1 = __float_as_uint(r1);
  const float mif = __uint_as_float(u1 & 0xFFFF0000u);
  const float r2 = r1 - mif;                     // exact
  hi.s[j] = (short)(u0 >> 16);
  mi.s[j] = (short)(u1 >> 16);
  lo.s[j] = (short)(__float_as_uint(r2) >> 16);
}

// 4-slot variant for wprep (same arithmetic -> same bf16 values)
__device__ __forceinline__ void split3w(float f, S4u& hi, S4u& mi, S4u& lo, int j) {
  const unsigned u0 = __float_as_uint(f);
  const float hif = __uint_as_float(u0 & 0xFFFF0000u);
  const float r1 = f - hif;
  const unsigned u1 = __float_as_uint(r1);
  const float mif = __uint_as_float(u1 & 0xFFFF0000u);
  const float r2 = r1 - mif;
  hi.s[j] = (short)(u0 >> 16);
  mi.s[j] = (short)(u1 >> 16);
  lo.s[j] = (short)(__float_as_uint(r2) >> 16);
}

// W planes precompute: wp[chunk][p][e][kk]
__global__ __launch_bounds__(256) void wprep(const float* __restrict__ w,
                                             short* __restrict__ wp) {
  const int gid = blockIdx.x * 256 + threadIdx.x;  // 65536 threads
  const int e = gid >> 9;                          // expert 0..127
  const int g = gid & 511;                         // float4 group in row
  const int k = g << 2;
  const int chunk = k >> 5;
  const int kk = k & 31;
  const f32x4 a = *(const f32x4*)(w + (size_t)e * DMODEL + k);
  S4u hi, mi, lo;
  split3w(a[0], hi, mi, lo, 0); split3w(a[1], hi, mi, lo, 1);
  split3w(a[2], hi, mi, lo, 2); split3w(a[3], hi, mi, lo, 3);
  short* base = wp + (size_t)chunk * CHUNK_SH + (size_t)e * KC + kk;
  *(s16x4*)(base)               = hi.v;
  *(s16x4*)(base + NE * KC)     = mi.v;
  *(s16x4*)(base + 2 * NE * KC) = lo.v;
}

__device__ __forceinline__ void gll16(const short* g, short* l) {
  __builtin_amdgcn_global_load_lds(
      (const __attribute__((address_space(1))) void*)g,
      (__attribute__((address_space(3))) void*)l, 16, 0, 0);
}

__global__ __launch_bounds__(256, 4) void logits_mfma(
    const float* __restrict__ x, const short* __restrict__ wp,
    float* __restrict__ part, int N) {
  // W image only: [plane][expert][k], single-buffered. 24 KB -> 4 blocks/CU.
  __shared__ __align__(16) short wsm[3][NE][KC];

  const int tid  = threadIdx.x;
  const int wave = tid >> 6;
  const int lane = tid & 63;
  const int wm = wave >> 1;        // token half (0..1): rows wm*32..
  const int wn = wave & 1;         // expert half (0..1)
  const int quad = lane >> 4;
  const int l16  = lane & 15;
  const size_t tokBase = (size_t)blockIdx.x * TOKT;
  const int d0 = blockIdx.y * DSLICE;
  const int chunkBase = blockIdx.y * NCH;

  // A-fragment global sources: row = wm*32 + mt*16 + l16, k = t*KC + quad*8
  const float* xg0 = x + (tokBase + wm * 32 + l16) * (size_t)DMODEL + d0 + quad * 8;
  const float* xg1 = xg0 + 16 * (size_t)DMODEL;    // mt=1 row

  f32x4 acc[2][4];
#pragma unroll
  for (int i = 0; i < 2; ++i)
#pragma unroll
    for (int j = 0; j < 4; ++j) acc[i][j] = (f32x4)(0.f);

  // ---- helpers ----
  auto stage_w = [&](int c) {      // 6x gll16: chunk c -> wsm (R10 pattern)
    const short* gsrc = wp + (size_t)(chunkBase + c) * CHUNK_SH + wave * 512 + lane * 8;
    short* ldst = &wsm[0][0][0] + wave * 512;      // wave-uniform dest
#pragma unroll
    for (int i = 0; i < 6; ++i)
      gll16(gsrc + i * 2048, ldst + i * 2048);
  };
  auto load_x = [&](float4 (&xr)[4], int t) {      // 8 floats per mt row
    const float* g0 = xg0 + t * KC;
    const float* g1 = xg1 + t * KC;
    xr[0] = *(const float4*)(g0);
    xr[1] = *(const float4*)(g0 + 4);
    xr[2] = *(const float4*)(g1);
    xr[3] = *(const float4*)(g1 + 4);
  };
  auto build_af = [&](short8 (&af)[2][3], const float4 (&xr)[4]) {
#pragma unroll
    for (int mt = 0; mt < 2; ++mt) {
      const float4 a0 = xr[2 * mt];
      const float4 a1 = xr[2 * mt + 1];
      S8 hi, mi, lo;
      split3(a0.x, hi, mi, lo, 0); split3(a0.y, hi, mi, lo, 1);
      split3(a0.z, hi, mi, lo, 2); split3(a0.w, hi, mi, lo, 3);
      split3(a1.x, hi, mi, lo, 4); split3(a1.y, hi, mi, lo, 5);
      split3(a1.z, hi, mi, lo, 6); split3(a1.w, hi, mi, lo, 7);
      af[mt][0] = hi.v; af[mt][1] = mi.v; af[mt][2] = lo.v;
    }
  };
  auto compute = [&](const short8 (&af)[2][3]) {
#pragma unroll
    for (int nt = 0; nt < 4; ++nt) {
      short8 bf[3];
#pragma unroll
      for (int p = 0; p < 3; ++p)
        bf[p] = *(const short8*)&wsm[p][wn * 64 + nt * 16 + l16][quad * 8];
#pragma unroll
      for (int mt = 0; mt < 2; ++mt) {
        f32x4 c = acc[mt][nt];
        c = __builtin_amdgcn_mfma_f32_16x16x32_bf16(af[mt][0], bf[0], c, 0, 0, 0); // x1w1
        c = __builtin_amdgcn_mfma_f32_16x16x32_bf16(af[mt][0], bf[1], c, 0, 0, 0); // x1w2
        c = __builtin_amdgcn_mfma_f32_16x16x32_bf16(af[mt][1], bf[0], c, 0, 0, 0); // x2w1
        c = __builtin_amdgcn_mfma_f32_16x16x32_bf16(af[mt][0], bf[2], c, 0, 0, 0); // x1w3
        c = __builtin_amdgcn_mfma_f32_16x16x32_bf16(af[mt][2], bf[0], c, 0, 0, 0); // x3w1
        c = __builtin_amdgcn_mfma_f32_16x16x32_bf16(af[mt][1], bf[1], c, 0, 0, 0); // x2w2
        acc[mt][nt] = c;
      }
    }
  };

  // ---- prologue: x(0) issued BEFORE gll(0) (older -> auto vmcnt(6) at use)
  float4 xa[4], xb[4];
  load_x(xa, 0);
  stage_w(0);

  short8 af[2][3];
#pragma unroll 1
  for (int t = 0; t < NCH; t += 2) {
    // even body: consume x(t)=xa, compute chunk t
    build_af(af, xa);                      // compiler waits xa only
    if (t + 1 < NCH) load_x(xb, t + 1);    // prefetch x(t+1)
    // outstanding: 6 gll(t) + 4 x(t+1) -> retire gll, keep x in flight
    if (t + 1 < NCH)
      asm volatile("s_waitcnt vmcnt(4)" ::: "memory");
    else
      asm volatile("s_waitcnt vmcnt(0)" ::: "memory");
    __builtin_amdgcn_s_barrier();          // wsm(t) complete for all waves
    __builtin_amdgcn_sched_barrier(0);
    compute(af);
    if (t + 1 < NCH) {
      __builtin_amdgcn_s_barrier();        // all waves done reading wsm(t)
      __builtin_amdgcn_sched_barrier(0);
      stage_w(t + 1);
      // odd body: consume x(t+1)=xb, compute chunk t+1
      build_af(af, xb);
      if (t + 2 < NCH) load_x(xa, t + 2);
      if (t + 2 < NCH)
        asm volatile("s_waitcnt vmcnt(4)" ::: "memory");
      else
        asm volatile("s_waitcnt vmcnt(0)" ::: "memory");
      __builtin_amdgcn_s_barrier();
      __builtin_amdgcn_sched_barrier(0);
      compute(af);
      if (t + 2 < NCH) {
        __builtin_amdgcn_s_barrier();
        __builtin_amdgcn_sched_barrier(0);
        stage_w(t + 2);
      }
    }
  }

  // ---- epilogue: partials[kb][tok][exp]; C/D: col=lane&15, row=quad*4+reg ----
#pragma unroll
  for (int mt = 0; mt < 2; ++mt)
#pragma unroll
    for (int nt = 0; nt < 4; ++nt) {
      const int ex = wn * 64 + nt * 16 + l16;
#pragma unroll
      for (int reg = 0; reg < 4; ++reg) {
        const size_t tok = tokBase + wm * 32 + mt * 16 + quad * 4 + reg;
        part[((size_t)blockIdx.y * N + tok) * NE + ex] = acc[mt][nt][reg];
      }
    }
}

// One wave (64 lanes) per token; lane owns experts {lane, lane+64}. (verbatim R3)
__global__ __launch_bounds__(256) void router_topk(
    const float* __restrict__ part, const float* __restrict__ bias,
    float* __restrict__ outW, float* __restrict__ outI, int ks, int N) {
  const int wave = threadIdx.x >> 6;
  const int lane = threadIdx.x & 63;
  const int token = blockIdx.x * 4 + wave;
  if (token >= N) return;

  float l0 = 0.f, l1 = 0.f;
  for (int k = 0; k < ks; ++k) {
    const float* p = part + ((size_t)k * N + token) * NE;
    l0 += p[lane];
    l1 += p[lane + 64];
  }

  float m = fmaxf(l0, l1);
#pragma unroll
  for (int off = 1; off < 64; off <<= 1) m = fmaxf(m, __shfl_xor(m, off));
  const float ev0 = __expf(l0 - m);
  const float ev1 = __expf(l1 - m);
  float zs = ev0 + ev1;
#pragma unroll
  for (int off = 1; off < 64; off <<= 1) zs += __shfl_xor(zs, off);
  const float s0 = ev0 / zs;
  const float s1 = ev1 / zs;

  float b0 = s0 + bias[lane];
  float b1 = s1 + bias[lane + 64];

  float myv = 0.f;
  int myi = 0;
  float ss = 0.f;
#pragma unroll
  for (int rnd = 0; rnd < 8; ++rnd) {
    float key; int idx;
    if (b0 >= b1) { key = b0; idx = lane; }
    else          { key = b1; idx = lane + 64; }
#pragma unroll
    for (int off = 1; off < 64; off <<= 1) {
      const float k2 = __shfl_xor(key, off);
      const int   i2 = __shfl_xor(idx, off);
      if (k2 > key || (k2 == key && i2 < idx)) { key = k2; idx = i2; }
    }
    const float cand = (idx < 64) ? s0 : s1;
    const float sw = __shfl(cand, idx & 63);
    ss = fmaf(sw, sw, ss);
    if (lane == rnd) { myv = sw; myi = idx; }
    if (lane == (idx & 63)) { if (idx < 64) b0 = -INFINITY; else b1 = -INFINITY; }
  }

  const float inv = 1.f / sqrtf(ss);
  if (lane < 8) {
    outW[(size_t)token * 8 + lane] = myv * inv;
    outI[(size_t)token * 8 + lane] = (float)myi;
  }
}

extern "C" void kernel_launch(void* const* d_in, const int* in_sizes, int n_in,
                              void* d_out, int out_size, void* d_ws, size_t ws_size,
                              hipStream_t stream) {
  const float* x    = (const float*)d_in[0];
  const float* w    = (const float*)d_in[1];
  const float* bias = (const float*)d_in[2];
  float* out = (float*)d_out;

  const int N = in_sizes[0] / DMODEL;        // 16384 tokens
  short* wp  = (short*)d_ws;                 // 1.5 MiB of W planes
  float* part = (float*)((char*)d_ws + (4 << 20));  // KS*N*128*4 B = 33.5 MB

  wprep<<<256, 256, 0, stream>>>(w, wp);
  logits_mfma<<<dim3(N / TOKT, KS), 256, 0, stream>>>(x, wp, part, N);
  router_topk<<<(N + 3) / 4, 256, 0, stream>>>(part, bias, out, out + (size_t)N * 8, KS, N);
}